// Round 6
// baseline (426.003 us; speedup 1.0000x reference)
//
#include <hip/hip_runtime.h>
#include <math.h>

#define NN 50000
#define NE 500000
#define NF 128
#define NO 16
#define NSL 8        // feature slices (16 features each)
#define SCAN_B 1024
#define NPART 16
#define EBL 1954     // (NE+255)/256

static_assert(NN < 65536, "src must fit u16");

typedef _Float16 f16x8 __attribute__((ext_vector_type(8)));
typedef float f32x4 __attribute__((ext_vector_type(4)));

union HU { unsigned short u; _Float16 h; };

__device__ inline float rec_w(unsigned int rec) {
    HU cu; cu.u = (unsigned short)(rec >> 16);
    return (float)cu.h;
}

// ---------------- graph preprocessing (atomic-light CSR build) ----------------

// pass 1: per-edge rank within (partition, dst); spare blocks transpose W1/W2 to fp16
__global__ void k_count_rank(const int* __restrict__ dst, int* __restrict__ pcnt,
                             int* __restrict__ rank, int E,
                             const float* __restrict__ W1, const float* __restrict__ W2,
                             _Float16* __restrict__ W1T, _Float16* __restrict__ W2T) {
    int b = blockIdx.x;
    if (b < EBL) {
        int part = b & (NPART - 1);
        int e = b * 256 + threadIdx.x;
        if (e < E) {
            int d = dst[e];
            rank[e] = atomicAdd(&pcnt[part * NN + d], 1);
        }
    } else {
        int idx = (b - EBL) * 256 + threadIdx.x;   // [0,16384)
        int r = idx >> 7, c = idx & 127;
        W1T[(size_t)c * NF + r] = (_Float16)W1[idx];
        W2T[(size_t)c * NF + r] = (_Float16)W2[idx];
    }
}

// pass 2: per-node partition bases (in place) + block-level exclusive scan of totals
__global__ void k_scan1f(int* __restrict__ pcnt, int* __restrict__ offs_p,
                         int* __restrict__ bsums, int N) {
    __shared__ int sm[SCAN_B];
    int t = threadIdx.x;
    int i = blockIdx.x * SCAN_B + t;
    int c = 0;
    if (i < N) {
        int run = 0;
#pragma unroll
        for (int p = 0; p < NPART; ++p) {
            int v = pcnt[p * NN + i];
            pcnt[p * NN + i] = run;
            run += v;
        }
        c = run;
    }
    sm[t] = c;
    __syncthreads();
    for (int off = 1; off < SCAN_B; off <<= 1) {
        int x = (t >= off) ? sm[t - off] : 0;
        __syncthreads();
        sm[t] += x;
        __syncthreads();
    }
    if (i < N) offs_p[i] = sm[t] - c;
    if (t == SCAN_B - 1) bsums[blockIdx.x] = sm[t];
}

// 64-lane shuffle scan (NB=49 <= 64)
__global__ void k_scan2(int* __restrict__ bsums, int NB) {
    int t = threadIdx.x;
    int v = (t < NB) ? bsums[t] : 0;
    int orig = v;
#pragma unroll
    for (int off = 1; off < 64; off <<= 1) {
        int u = __shfl_up(v, off, 64);
        if (t >= off) v += u;
    }
    if (t < NB) bsums[t] = v - orig;
}

// pass 3: finalize offs; fold node offset into every partition base
__global__ void k_scan3x(const int* __restrict__ offs_p, const int* __restrict__ bsums,
                         int* __restrict__ pcnt, int* __restrict__ offs_f, int E) {
    int i = blockIdx.x * blockDim.x + threadIdx.x;
    if (i < NPART * NN) {
        int p = i / NN;
        int n = i - p * NN;
        int v = offs_p[n] + bsums[n >> 10];
        pcnt[i] += v;
        if (p == 0) offs_f[n] = v;
    } else if (i == NPART * NN) {
        offs_f[NN] = E;
    }
}

// pass 4: atomic-free scatter of packed 4B {src:u16, ew:fp16} records
__global__ void k_scatter(const int* __restrict__ src, const int* __restrict__ dst,
                          const float* __restrict__ ew, const int* __restrict__ pcnt,
                          const int* __restrict__ rank, unsigned int* __restrict__ erec, int E) {
    int part = blockIdx.x & (NPART - 1);
    int e = blockIdx.x * blockDim.x + threadIdx.x;
    if (e < E) {
        int d = dst[e];
        int pos = pcnt[part * NN + d] + rank[e];
        HU cu; cu.h = (_Float16)ew[e];
        erec[pos] = (unsigned int)src[e] | ((unsigned int)cu.u << 16);
    }
}

// pass 5: deg from CSR -> dinv
__global__ void k_dinv_csr(const unsigned int* __restrict__ erec, const int* __restrict__ offs,
                           float* __restrict__ dinv, int N) {
    int n = blockIdx.x * blockDim.x + threadIdx.x;
    if (n < N) {
        float deg = 1.0f;
        int s = offs[n], e = offs[n + 1];
        for (int j = s; j < e; ++j) deg += rec_w(erec[j]);
        dinv[n] = rsqrtf(deg);
    }
}

// ---------------- MFMA GEMM: Z = dinv ⊙ (X @ W), output SLICE-MAJOR fp16 ----------------
// Z layout: Z[((slice*NN + node) << 4) + f_local], slice = f >> 4.

__device__ inline f16x8 afrag_load_f32(const float* X, int row, int k0) {
    const float4* p = (const float4*)(X + (size_t)row * NF + k0);
    float4 a = p[0], b = p[1];
    f16x8 r;
    r[0] = (_Float16)a.x; r[1] = (_Float16)a.y; r[2] = (_Float16)a.z; r[3] = (_Float16)a.w;
    r[4] = (_Float16)b.x; r[5] = (_Float16)b.y; r[6] = (_Float16)b.z; r[7] = (_Float16)b.w;
    return r;
}

template <typename TA, bool ASLICE>
__global__ __launch_bounds__(256) void k_gemm_mfma(const TA* __restrict__ X,
                                                   const _Float16* __restrict__ WT,
                                                   const float* __restrict__ dinv,
                                                   _Float16* __restrict__ Z, int M) {
    __shared__ _Float16 ls[4][16 * 136];      // padded stride 136 halves
    const int tid  = threadIdx.x;
    const int w    = tid >> 6;
    const int lane = tid & 63;
    const int n16  = lane & 15;
    const int quad = lane >> 4;
    const int r0   = blockIdx.x * 64 + w * 16;

    int arow = r0 + n16; if (arow > M - 1) arow = M - 1;

    f32x4 acc[8];
#pragma unroll
    for (int c = 0; c < 8; ++c) acc[c] = (f32x4){0.f, 0.f, 0.f, 0.f};

#pragma unroll
    for (int kk = 0; kk < 4; ++kk) {
        int k0 = kk * 32 + quad * 8;
        f16x8 a;
        if constexpr (ASLICE) {
            int s = k0 >> 4;
            a = *(const f16x8*)(X + (((size_t)s * NN + arow) << 4) + (k0 & 15));
        } else {
            a = afrag_load_f32(X, arow, k0);
        }
#pragma unroll
        for (int c = 0; c < 8; ++c) {
            f16x8 b = *(const f16x8*)(WT + (size_t)(c * 16 + n16) * NF + k0);
            acc[c] = __builtin_amdgcn_mfma_f32_16x16x32_f16(a, b, acc[c], 0, 0, 0);
        }
    }

    // epilogue: scale by dinv[row], fp16, repack via LDS
#pragma unroll
    for (int reg = 0; reg < 4; ++reg) {
        int lrow = quad * 4 + reg;
        int grow = r0 + lrow; if (grow > M - 1) grow = M - 1;
        float di = dinv[grow];
#pragma unroll
        for (int c = 0; c < 8; ++c)
            ls[w][lrow * 136 + c * 16 + n16] = (_Float16)(acc[c][reg] * di);
    }
    __syncthreads();
    // slice-major coalesced stores: 2 slices per iteration
#pragma unroll
    for (int it = 0; it < 4; ++it) {
        int s   = it * 2 + (lane >> 5);
        int row = (lane >> 1) & 15;
        int fc  = lane & 1;
        int grow = r0 + row;
        if (grow < M) {
            f16x8 v = *(const f16x8*)(&ls[w][row * 136 + s * 16 + fc * 8]);
            *(f16x8*)(Z + (((size_t)s * NN + grow) << 4) + fc * 8) = v;
        }
    }
}

// ---------------- slice aggregation: h = [relu](dinv_n*(z_n + sum ew*z_src) + b) ----------------
// slice = blockIdx & 7 (XCD affinity); wave = 1 node; lanes = 16 features x 4 edge slots.
__global__ __launch_bounds__(256) void k_agg_slice(const _Float16* __restrict__ z_s,
                                                   const float* __restrict__ dinv,
                                                   const int* __restrict__ offs,
                                                   const unsigned int* __restrict__ erec,
                                                   const float* __restrict__ bias,
                                                   _Float16* __restrict__ h_s, int relu) {
    const int tid   = threadIdx.x;
    const int lane  = tid & 63;
    const int f     = lane & 15;
    const int eslot = lane >> 4;
    const int slice = blockIdx.x & (NSL - 1);
    const int n     = (blockIdx.x >> 3) * 4 + (tid >> 6);

    const size_t sbase = ((size_t)slice * NN) << 4;

    int s0 = offs[n], e0 = offs[n + 1];
    float acc = 0.0f;
    for (int j0 = s0; j0 < e0; j0 += 4) {
        int idx = j0 + eslot;
        unsigned int rec = 0u;
        if (idx < e0) rec = erec[idx];
        int sn = rec & 0xFFFF;
        float wv = rec_w(rec);
        float val = (float)z_s[sbase + ((size_t)sn << 4) + f];
        acc = fmaf(val, wv, acc);
    }
    acc += __shfl_xor(acc, 16, 64);
    acc += __shfl_xor(acc, 32, 64);

    float self = (float)z_s[sbase + ((size_t)n << 4) + f];
    float r = fmaf(dinv[n], self + acc, bias[slice * 16 + f]);
    if (relu) r = fmaxf(r, 0.0f);
    if (eslot == 0) h_s[sbase + ((size_t)n << 4) + f] = (_Float16)r;
}

// ---------------- GEMM: Z3[M,16](fp16) = dinv ⊙ (H_slice @ W3[128,16]) ----------------
__global__ __launch_bounds__(256) void k_gemm16(const _Float16* __restrict__ H,
                                                const float* __restrict__ W3,
                                                const float* __restrict__ dinv,
                                                _Float16* __restrict__ Z3, int M) {
    __shared__ float Wl[NF * NO];
    __shared__ float Hs[16 * 132];
    int tid = threadIdx.x;
    for (int i = tid; i < NF * NO; i += 256) Wl[i] = W3[i];
    int n0 = blockIdx.x * 16;
    {
        int row = tid >> 4, h8 = tid & 15;
        int gr = n0 + row; if (gr > M - 1) gr = M - 1;
        int s = h8 >> 1, off = (h8 & 1) * 8;
        f16x8 v = *(const f16x8*)(H + (((size_t)s * NN + gr) << 4) + off);
        float4 f0 = {(float)v[0], (float)v[1], (float)v[2], (float)v[3]};
        float4 f1 = {(float)v[4], (float)v[5], (float)v[6], (float)v[7]};
        *(float4*)(&Hs[row * 132 + h8 * 8])     = f0;
        *(float4*)(&Hs[row * 132 + h8 * 8 + 4]) = f1;
    }
    __syncthreads();
    int ln = tid >> 4, c = tid & 15;
    float acc = 0.0f;
#pragma unroll 8
    for (int k = 0; k < NF; ++k) acc = fmaf(Hs[ln * 132 + k], Wl[k * NO + c], acc);
    int n = n0 + ln;
    if (n < M) Z3[(size_t)n * NO + c] = (_Float16)(acc * dinv[n]);
}

// ---------------- final aggregation (16-wide, fp16 table) + bias + log_softmax ----------------
__global__ __launch_bounds__(256) void k_agg16_ls(const _Float16* __restrict__ z3,
                                                  const float* __restrict__ dinv,
                                                  const int* __restrict__ offs,
                                                  const unsigned int* __restrict__ erec,
                                                  const float* __restrict__ bias,
                                                  float* __restrict__ out) {
    int tid = threadIdx.x;
    int ln = tid >> 4, c = tid & 15;
    int n = blockIdx.x * 16 + ln;
    float acc = (float)z3[((size_t)n << 4) + c];
    int s = offs[n], e = offs[n + 1];
    int j = s;
    for (; j + 1 < e; j += 2) {
        unsigned int r0 = erec[j], r1 = erec[j + 1];
        acc = fmaf((float)z3[((size_t)(r0 & 0xFFFF) << 4) + c], rec_w(r0), acc);
        acc = fmaf((float)z3[((size_t)(r1 & 0xFFFF) << 4) + c], rec_w(r1), acc);
    }
    if (j < e) {
        unsigned int r0 = erec[j];
        acc = fmaf((float)z3[((size_t)(r0 & 0xFFFF) << 4) + c], rec_w(r0), acc);
    }
    acc = fmaf(dinv[n], acc, bias[c]);
    float m = acc;
#pragma unroll
    for (int off = 8; off > 0; off >>= 1) m = fmaxf(m, __shfl_xor(m, off, 16));
    float ex = expf(acc - m);
    float ss = ex;
#pragma unroll
    for (int off = 8; off > 0; off >>= 1) ss += __shfl_xor(ss, off, 16);
    out[(size_t)n * NO + c] = acc - m - logf(ss);
}

// ---------------- launch ----------------

extern "C" void kernel_launch(void* const* d_in, const int* in_sizes, int n_in,
                              void* d_out, int out_size, void* d_ws, size_t ws_size,
                              hipStream_t stream) {
    const float* x   = (const float*)d_in[0];
    const int*   esrc= (const int*)  d_in[1];
    const int*   edst= (const int*)  d_in[2];
    const float* ew  = (const float*)d_in[3];
    const float* W1  = (const float*)d_in[4];
    const float* b1  = (const float*)d_in[5];
    const float* W2  = (const float*)d_in[6];
    const float* b2  = (const float*)d_in[7];
    const float* W3  = (const float*)d_in[8];
    const float* b3  = (const float*)d_in[9];
    float* out = (float*)d_out;

    // workspace carve
    char* p = (char*)d_ws;
    _Float16* z   = (_Float16*)p; p += (size_t)NN * NF * 2;   // slice-major, 12.8 MB
    _Float16* h   = (_Float16*)p; p += (size_t)NN * NF * 2;   // slice-major, 12.8 MB
    _Float16* z3  = (_Float16*)p; p += (size_t)NN * NO * 2;   // 1.6 MB
    float* dinv   = (float*)p; p += (size_t)NN * 4;
    unsigned int* erec = (unsigned int*)p; p += (size_t)NE * 4;  // packed 4B records
    int*   rank   = (int*)p;   p += (size_t)NE * 4;
    int*   pcnt   = (int*)p;   p += (size_t)NPART * NN * 4;   // 3.2 MB
    int*   offs_p = (int*)p;   p += (size_t)(NN + 1) * 4;
    int*   offs_f = (int*)p;   p += (size_t)(NN + 1) * 4;
    int*   bsums  = (int*)p;   p += 256;
    _Float16* W1T = (_Float16*)p; p += (size_t)NF * NF * 2;
    _Float16* W2T = (_Float16*)p; p += (size_t)NF * NF * 2;

    const int NB  = (NN + SCAN_B - 1) / SCAN_B;   // 49
    const int NBL = (NN + 255) / 256;

    hipMemsetAsync(pcnt, 0, (size_t)NPART * NN * 4, stream);

    k_count_rank<<<EBL + 64, 256, 0, stream>>>(edst, pcnt, rank, NE, W1, W2, W1T, W2T);
    k_scan1f<<<NB, SCAN_B, 0, stream>>>(pcnt, offs_p, bsums, NN);
    k_scan2<<<1, 64, 0, stream>>>(bsums, NB);
    k_scan3x<<<(NPART * NN + 256) / 256, 256, 0, stream>>>(offs_p, bsums, pcnt, offs_f, NE);
    k_scatter<<<EBL, 256, 0, stream>>>(esrc, edst, ew, pcnt, rank, erec, NE);
    k_dinv_csr<<<NBL, 256, 0, stream>>>(erec, offs_f, dinv, NN);

    const int AGG_GRID = (NN / 4) * NSL;   // 100000
    // layer 1
    k_gemm_mfma<float, false><<<(NN + 63) / 64, 256, 0, stream>>>(x, W1T, dinv, z, NN);
    k_agg_slice<<<AGG_GRID, 256, 0, stream>>>(z, dinv, offs_f, erec, b1, h, 1);
    // layer 2
    k_gemm_mfma<_Float16, true><<<(NN + 63) / 64, 256, 0, stream>>>(h, W2T, dinv, z, NN);
    k_agg_slice<<<AGG_GRID, 256, 0, stream>>>(z, dinv, offs_f, erec, b2, h, 1);
    // layer 3
    k_gemm16<<<(NN + 15) / 16, 256, 0, stream>>>(h, W3, dinv, z3, NN);
    k_agg16_ls<<<NN / 16, 256, 0, stream>>>(z3, dinv, offs_f, erec, b3, out);
}

// Round 7
// 251.045 us; speedup vs baseline: 1.6969x; 1.6969x over previous
//
#include <hip/hip_runtime.h>
#include <math.h>

#define NN 50000
#define NE 500000
#define NF 128
#define NO 16
#define SCAN_B 1024
#define NPART 16
#define EBL 1954     // (NE+255)/256

static_assert(NN < 65536, "src must fit u16");

typedef _Float16 f16x8 __attribute__((ext_vector_type(8)));
typedef _Float16 f16x4 __attribute__((ext_vector_type(4)));
typedef float f32x4 __attribute__((ext_vector_type(4)));

union HU { unsigned short u; _Float16 h; };

__device__ inline float rec_w(unsigned int rec) {
    HU cu; cu.u = (unsigned short)(rec >> 16);
    return (float)cu.h;
}

// ---------------- graph preprocessing (atomic-light CSR build) ----------------

// pass 1: per-edge rank within (partition, dst); spare blocks transpose W1/W2 to fp16
__global__ void k_count_rank(const int* __restrict__ dst, int* __restrict__ pcnt,
                             int* __restrict__ rank, int E,
                             const float* __restrict__ W1, const float* __restrict__ W2,
                             _Float16* __restrict__ W1T, _Float16* __restrict__ W2T) {
    int b = blockIdx.x;
    if (b < EBL) {
        int part = b & (NPART - 1);
        int e = b * 256 + threadIdx.x;
        if (e < E) {
            int d = dst[e];
            rank[e] = atomicAdd(&pcnt[part * NN + d], 1);
        }
    } else {
        int idx = (b - EBL) * 256 + threadIdx.x;   // [0,16384)
        int r = idx >> 7, c = idx & 127;
        W1T[(size_t)c * NF + r] = (_Float16)W1[idx];
        W2T[(size_t)c * NF + r] = (_Float16)W2[idx];
    }
}

// pass 2: per-node partition bases (in place) + block-level exclusive scan of totals
__global__ void k_scan1f(int* __restrict__ pcnt, int* __restrict__ offs_p,
                         int* __restrict__ bsums, int N) {
    __shared__ int sm[SCAN_B];
    int t = threadIdx.x;
    int i = blockIdx.x * SCAN_B + t;
    int c = 0;
    if (i < N) {
        int run = 0;
#pragma unroll
        for (int p = 0; p < NPART; ++p) {
            int v = pcnt[p * NN + i];
            pcnt[p * NN + i] = run;
            run += v;
        }
        c = run;
    }
    sm[t] = c;
    __syncthreads();
    for (int off = 1; off < SCAN_B; off <<= 1) {
        int x = (t >= off) ? sm[t - off] : 0;
        __syncthreads();
        sm[t] += x;
        __syncthreads();
    }
    if (i < N) offs_p[i] = sm[t] - c;
    if (t == SCAN_B - 1) bsums[blockIdx.x] = sm[t];
}

// 64-lane shuffle scan (NB=49 <= 64)
__global__ void k_scan2(int* __restrict__ bsums, int NB) {
    int t = threadIdx.x;
    int v = (t < NB) ? bsums[t] : 0;
    int orig = v;
#pragma unroll
    for (int off = 1; off < 64; off <<= 1) {
        int u = __shfl_up(v, off, 64);
        if (t >= off) v += u;
    }
    if (t < NB) bsums[t] = v - orig;
}

// pass 3: finalize offs; fold node offset into every partition base
__global__ void k_scan3x(const int* __restrict__ offs_p, const int* __restrict__ bsums,
                         int* __restrict__ pcnt, int* __restrict__ offs_f, int E) {
    int i = blockIdx.x * blockDim.x + threadIdx.x;
    if (i < NPART * NN) {
        int p = i / NN;
        int n = i - p * NN;
        int v = offs_p[n] + bsums[n >> 10];
        pcnt[i] += v;
        if (p == 0) offs_f[n] = v;
    } else if (i == NPART * NN) {
        offs_f[NN] = E;
    }
}

// pass 4: atomic-free scatter of packed 4B {src:u16, ew:fp16} records
__global__ void k_scatter(const int* __restrict__ src, const int* __restrict__ dst,
                          const float* __restrict__ ew, const int* __restrict__ pcnt,
                          const int* __restrict__ rank, unsigned int* __restrict__ erec, int E) {
    int part = blockIdx.x & (NPART - 1);
    int e = blockIdx.x * blockDim.x + threadIdx.x;
    if (e < E) {
        int d = dst[e];
        int pos = pcnt[part * NN + d] + rank[e];
        HU cu; cu.h = (_Float16)ew[e];
        erec[pos] = (unsigned int)src[e] | ((unsigned int)cu.u << 16);
    }
}

// pass 5: deg from CSR -> dinv
__global__ void k_dinv_csr(const unsigned int* __restrict__ erec, const int* __restrict__ offs,
                           float* __restrict__ dinv, int N) {
    int n = blockIdx.x * blockDim.x + threadIdx.x;
    if (n < N) {
        float deg = 1.0f;
        int s = offs[n], e = offs[n + 1];
        for (int j = s; j < e; ++j) deg += rec_w(erec[j]);
        dinv[n] = rsqrtf(deg);
    }
}

// ---------------- MFMA GEMM: Z[M,128](fp16, row-major) = dinv ⊙ (X @ W) ----------------

__device__ inline f16x8 afrag_load(const float* X, int row, int k0) {
    const float4* p = (const float4*)(X + (size_t)row * NF + k0);
    float4 a = p[0], b = p[1];
    f16x8 r;
    r[0] = (_Float16)a.x; r[1] = (_Float16)a.y; r[2] = (_Float16)a.z; r[3] = (_Float16)a.w;
    r[4] = (_Float16)b.x; r[5] = (_Float16)b.y; r[6] = (_Float16)b.z; r[7] = (_Float16)b.w;
    return r;
}
__device__ inline f16x8 afrag_load(const _Float16* X, int row, int k0) {
    return *(const f16x8*)(X + (size_t)row * NF + k0);
}

template <typename TA>
__global__ __launch_bounds__(256) void k_gemm_mfma(const TA* __restrict__ X,
                                                   const _Float16* __restrict__ WT,
                                                   const float* __restrict__ dinv,
                                                   _Float16* __restrict__ Z, int M) {
    __shared__ _Float16 ls[4][16 * 136];      // padded stride 136 halves
    const int tid  = threadIdx.x;
    const int w    = tid >> 6;
    const int lane = tid & 63;
    const int n16  = lane & 15;
    const int quad = lane >> 4;
    const int r0   = blockIdx.x * 64 + w * 16;

    int arow = r0 + n16; if (arow > M - 1) arow = M - 1;

    f32x4 acc[8];
#pragma unroll
    for (int c = 0; c < 8; ++c) acc[c] = (f32x4){0.f, 0.f, 0.f, 0.f};

#pragma unroll
    for (int kk = 0; kk < 4; ++kk) {
        int k0 = kk * 32 + quad * 8;
        f16x8 a = afrag_load(X, arow, k0);
#pragma unroll
        for (int c = 0; c < 8; ++c) {
            f16x8 b = *(const f16x8*)(WT + (size_t)(c * 16 + n16) * NF + k0);
            acc[c] = __builtin_amdgcn_mfma_f32_16x16x32_f16(a, b, acc[c], 0, 0, 0);
        }
    }

    // epilogue: scale by dinv[row], fp16, repack via LDS for coalesced stores
#pragma unroll
    for (int reg = 0; reg < 4; ++reg) {
        int lrow = quad * 4 + reg;
        int grow = r0 + lrow; if (grow > M - 1) grow = M - 1;
        float di = dinv[grow];
#pragma unroll
        for (int c = 0; c < 8; ++c)
            ls[w][lrow * 136 + c * 16 + n16] = (_Float16)(acc[c][reg] * di);
    }
    __syncthreads();
#pragma unroll
    for (int i = 0; i < 4; ++i) {
        int off16 = i * 64 + lane;            // 16B chunk index in this wave's tile
        int row = off16 >> 4;
        int col = off16 & 15;
        int grow = r0 + row;
        if (grow < M) {
            f16x8 v = *(const f16x8*)(&ls[w][row * 136 + col * 8]);
            *(f16x8*)(Z + (size_t)grow * NF + col * 8) = v;
        }
    }
}

// ---------------- aggregation, 128-wide, dual-edge 8B gathers ----------------
// 1 wave per node. lane = (half, li): half = edge parity, li = 4-feature chunk.
// Each gather instr: 64 lanes x 8B = 2 edges x 256B of row data.
__global__ __launch_bounds__(256) void k_agg128h(const _Float16* __restrict__ z,
                                                 const float* __restrict__ dinv,
                                                 const int* __restrict__ offs,
                                                 const unsigned int* __restrict__ erec,
                                                 const float* __restrict__ bias,
                                                 _Float16* __restrict__ hout, int relu) {
    const int tid  = threadIdx.x;
    const int lane = tid & 63;
    const int half = lane >> 5;      // edge parity
    const int li   = lane & 31;      // feature chunk [li*4, li*4+4)
    int n = __builtin_amdgcn_readfirstlane(blockIdx.x * 4 + (tid >> 6));

    float acc0 = 0.f, acc1 = 0.f, acc2 = 0.f, acc3 = 0.f;

    int s = offs[n], e = offs[n + 1];
    for (int base = s; base < e; base += 64) {
        int cnt = e - base; if (cnt > 64) cnt = 64;
        unsigned int rec = 0u;
        if (lane < cnt) rec = erec[base + lane];
        int   my_s = rec & 0xFFFF;
        float my_w = rec_w(rec);
        int k = 0;
        for (; k + 7 < cnt; k += 8) {
            int e0 = k + half, e1 = k + 2 + half, e2 = k + 4 + half, e3 = k + 6 + half;
            int s0 = __shfl(my_s, e0, 64), s1 = __shfl(my_s, e1, 64);
            int s2 = __shfl(my_s, e2, 64), s3 = __shfl(my_s, e3, 64);
            float w0 = __shfl(my_w, e0, 64), w1 = __shfl(my_w, e1, 64);
            float w2 = __shfl(my_w, e2, 64), w3 = __shfl(my_w, e3, 64);
            f16x4 v0 = *(const f16x4*)(z + ((size_t)s0 << 7) + li * 4);
            f16x4 v1 = *(const f16x4*)(z + ((size_t)s1 << 7) + li * 4);
            f16x4 v2 = *(const f16x4*)(z + ((size_t)s2 << 7) + li * 4);
            f16x4 v3 = *(const f16x4*)(z + ((size_t)s3 << 7) + li * 4);
            acc0 = fmaf((float)v0[0], w0, acc0); acc1 = fmaf((float)v0[1], w0, acc1);
            acc2 = fmaf((float)v0[2], w0, acc2); acc3 = fmaf((float)v0[3], w0, acc3);
            acc0 = fmaf((float)v1[0], w1, acc0); acc1 = fmaf((float)v1[1], w1, acc1);
            acc2 = fmaf((float)v1[2], w1, acc2); acc3 = fmaf((float)v1[3], w1, acc3);
            acc0 = fmaf((float)v2[0], w2, acc0); acc1 = fmaf((float)v2[1], w2, acc1);
            acc2 = fmaf((float)v2[2], w2, acc2); acc3 = fmaf((float)v2[3], w2, acc3);
            acc0 = fmaf((float)v3[0], w3, acc0); acc1 = fmaf((float)v3[1], w3, acc1);
            acc2 = fmaf((float)v3[2], w3, acc2); acc3 = fmaf((float)v3[3], w3, acc3);
        }
        for (; k < cnt; k += 2) {
            int eidx = k + half;
            int ec = eidx < cnt ? eidx : cnt - 1;
            int   s0 = __shfl(my_s, ec, 64);
            float wt = __shfl(my_w, ec, 64);
            float w0 = (eidx < cnt) ? wt : 0.0f;
            f16x4 v0 = *(const f16x4*)(z + ((size_t)s0 << 7) + li * 4);
            acc0 = fmaf((float)v0[0], w0, acc0); acc1 = fmaf((float)v0[1], w0, acc1);
            acc2 = fmaf((float)v0[2], w0, acc2); acc3 = fmaf((float)v0[3], w0, acc3);
        }
    }
    // merge edge-parity halves
    acc0 += __shfl_xor(acc0, 32, 64);
    acc1 += __shfl_xor(acc1, 32, 64);
    acc2 += __shfl_xor(acc2, 32, 64);
    acc3 += __shfl_xor(acc3, 32, 64);

    // self + bias + relu
    f16x4 sv = *(const f16x4*)(z + ((size_t)n << 7) + li * 4);
    float di = dinv[n];
    float4 bb = *(const float4*)(bias + li * 4);
    float r0 = fmaf(di, (float)sv[0] + acc0, bb.x);
    float r1 = fmaf(di, (float)sv[1] + acc1, bb.y);
    float r2 = fmaf(di, (float)sv[2] + acc2, bb.z);
    float r3 = fmaf(di, (float)sv[3] + acc3, bb.w);
    if (relu) {
        r0 = fmaxf(r0, 0.0f); r1 = fmaxf(r1, 0.0f);
        r2 = fmaxf(r2, 0.0f); r3 = fmaxf(r3, 0.0f);
    }
    if (half == 0) {
        f16x4 o;
        o[0] = (_Float16)r0; o[1] = (_Float16)r1;
        o[2] = (_Float16)r2; o[3] = (_Float16)r3;
        *(f16x4*)(hout + ((size_t)n << 7) + li * 4) = o;
    }
}

// ---------------- GEMM: Z3[M,16](fp16) = dinv ⊙ (H[M,128](fp16) @ W3[128,16]) ----------------
__global__ __launch_bounds__(256) void k_gemm16(const _Float16* __restrict__ H,
                                                const float* __restrict__ W3,
                                                const float* __restrict__ dinv,
                                                _Float16* __restrict__ Z3, int M) {
    __shared__ float Wl[NF * NO];
    __shared__ float Hs[16 * 132];
    int tid = threadIdx.x;
    for (int i = tid; i < NF * NO; i += 256) Wl[i] = W3[i];
    int n0 = blockIdx.x * 16;
    {
        int row = tid >> 4, h8 = tid & 15;
        int gr = n0 + row; if (gr > M - 1) gr = M - 1;
        f16x8 v = *(const f16x8*)(H + (size_t)gr * NF + h8 * 8);
        float4 f0 = {(float)v[0], (float)v[1], (float)v[2], (float)v[3]};
        float4 f1 = {(float)v[4], (float)v[5], (float)v[6], (float)v[7]};
        *(float4*)(&Hs[row * 132 + h8 * 8])     = f0;
        *(float4*)(&Hs[row * 132 + h8 * 8 + 4]) = f1;
    }
    __syncthreads();
    int ln = tid >> 4, c = tid & 15;
    float acc = 0.0f;
#pragma unroll 8
    for (int k = 0; k < NF; ++k) acc = fmaf(Hs[ln * 132 + k], Wl[k * NO + c], acc);
    int n = n0 + ln;
    if (n < M) Z3[(size_t)n * NO + c] = (_Float16)(acc * dinv[n]);
}

// ---------------- final aggregation (16-wide, fp16 table) + bias + log_softmax ----------------
__global__ __launch_bounds__(256) void k_agg16_ls(const _Float16* __restrict__ z3,
                                                  const float* __restrict__ dinv,
                                                  const int* __restrict__ offs,
                                                  const unsigned int* __restrict__ erec,
                                                  const float* __restrict__ bias,
                                                  float* __restrict__ out) {
    int tid = threadIdx.x;
    int ln = tid >> 4, c = tid & 15;
    int n = blockIdx.x * 16 + ln;
    float acc = (float)z3[((size_t)n << 4) + c];
    int s = offs[n], e = offs[n + 1];
    int j = s;
    for (; j + 1 < e; j += 2) {
        unsigned int r0 = erec[j], r1 = erec[j + 1];
        acc = fmaf((float)z3[((size_t)(r0 & 0xFFFF) << 4) + c], rec_w(r0), acc);
        acc = fmaf((float)z3[((size_t)(r1 & 0xFFFF) << 4) + c], rec_w(r1), acc);
    }
    if (j < e) {
        unsigned int r0 = erec[j];
        acc = fmaf((float)z3[((size_t)(r0 & 0xFFFF) << 4) + c], rec_w(r0), acc);
    }
    acc = fmaf(dinv[n], acc, bias[c]);
    float m = acc;
#pragma unroll
    for (int off = 8; off > 0; off >>= 1) m = fmaxf(m, __shfl_xor(m, off, 16));
    float ex = expf(acc - m);
    float ss = ex;
#pragma unroll
    for (int off = 8; off > 0; off >>= 1) ss += __shfl_xor(ss, off, 16);
    out[(size_t)n * NO + c] = acc - m - logf(ss);
}

// ---------------- launch ----------------

extern "C" void kernel_launch(void* const* d_in, const int* in_sizes, int n_in,
                              void* d_out, int out_size, void* d_ws, size_t ws_size,
                              hipStream_t stream) {
    const float* x   = (const float*)d_in[0];
    const int*   esrc= (const int*)  d_in[1];
    const int*   edst= (const int*)  d_in[2];
    const float* ew  = (const float*)d_in[3];
    const float* W1  = (const float*)d_in[4];
    const float* b1  = (const float*)d_in[5];
    const float* W2  = (const float*)d_in[6];
    const float* b2  = (const float*)d_in[7];
    const float* W3  = (const float*)d_in[8];
    const float* b3  = (const float*)d_in[9];
    float* out = (float*)d_out;

    // workspace carve
    char* p = (char*)d_ws;
    _Float16* z   = (_Float16*)p; p += (size_t)NN * NF * 2;   // row-major, 12.8 MB
    _Float16* h   = (_Float16*)p; p += (size_t)NN * NF * 2;   // row-major, 12.8 MB
    _Float16* z3  = (_Float16*)p; p += (size_t)NN * NO * 2;   // 1.6 MB
    float* dinv   = (float*)p; p += (size_t)NN * 4;
    unsigned int* erec = (unsigned int*)p; p += (size_t)NE * 4;  // packed 4B records
    int*   rank   = (int*)p;   p += (size_t)NE * 4;
    int*   pcnt   = (int*)p;   p += (size_t)NPART * NN * 4;   // 3.2 MB
    int*   offs_p = (int*)p;   p += (size_t)(NN + 1) * 4;
    int*   offs_f = (int*)p;   p += (size_t)(NN + 1) * 4;
    int*   bsums  = (int*)p;   p += 256;
    _Float16* W1T = (_Float16*)p; p += (size_t)NF * NF * 2;
    _Float16* W2T = (_Float16*)p; p += (size_t)NF * NF * 2;

    const int NB  = (NN + SCAN_B - 1) / SCAN_B;   // 49
    const int NBL = (NN + 255) / 256;

    hipMemsetAsync(pcnt, 0, (size_t)NPART * NN * 4, stream);

    k_count_rank<<<EBL + 64, 256, 0, stream>>>(edst, pcnt, rank, NE, W1, W2, W1T, W2T);
    k_scan1f<<<NB, SCAN_B, 0, stream>>>(pcnt, offs_p, bsums, NN);
    k_scan2<<<1, 64, 0, stream>>>(bsums, NB);
    k_scan3x<<<(NPART * NN + 256) / 256, 256, 0, stream>>>(offs_p, bsums, pcnt, offs_f, NE);
    k_scatter<<<EBL, 256, 0, stream>>>(esrc, edst, ew, pcnt, rank, erec, NE);
    k_dinv_csr<<<NBL, 256, 0, stream>>>(erec, offs_f, dinv, NN);

    // layer 1
    k_gemm_mfma<float><<<(NN + 63) / 64, 256, 0, stream>>>(x, W1T, dinv, z, NN);
    k_agg128h<<<NN / 4, 256, 0, stream>>>(z, dinv, offs_f, erec, b1, h, 1);
    // layer 2
    k_gemm_mfma<_Float16><<<(NN + 63) / 64, 256, 0, stream>>>(h, W2T, dinv, z, NN);
    k_agg128h<<<NN / 4, 256, 0, stream>>>(z, dinv, offs_f, erec, b2, h, 1);
    // layer 3
    k_gemm16<<<(NN + 15) / 16, 256, 0, stream>>>(h, W3, dinv, z3, NN);
    k_agg16_ls<<<NN / 16, 256, 0, stream>>>(z3, dinv, offs_f, erec, b3, out);
}